// Round 21
// baseline (645.267 us; speedup 1.0000x reference)
//
#include <hip/hip_runtime.h>

#define NFEAT 64

// Environment (proven by R20 deployed PASS): feat=f32, edge indices=int32,
// e1=edge_src, e2=edge_dst, output=f32. Bounds guards kept (poison safety).

__global__ void v21_zero(int* __restrict__ deg_out, int* __restrict__ deg_in,
                         int n_src, int n_dst) {
    int i = blockIdx.x * blockDim.x + threadIdx.x;
    if (i < n_src) deg_out[i] = 0;
    if (i < n_dst) deg_in[i] = 0;
}

__global__ void v21_deg(const int* __restrict__ esrc, const int* __restrict__ edst,
                        int* __restrict__ deg_out, int* __restrict__ deg_in,
                        int E, int n_src, int n_dst) {
    int i = blockIdx.x * blockDim.x + threadIdx.x;
    if (i >= E) return;
    int s = esrc[i];
    int d = edst[i];
    if ((unsigned)s < (unsigned)n_src) atomicAdd(&deg_out[s], 1);
    if ((unsigned)d < (unsigned)n_dst) atomicAdd(&deg_in[d], 1);
}

// norms + exclusive scan of deg_in -> row_start, cursor. Single block.
__global__ void v21_scan(const int* __restrict__ deg_out, const int* __restrict__ deg_in,
                         float* __restrict__ nsrc, float* __restrict__ ndst,
                         int* __restrict__ row_start, int* __restrict__ cursor,
                         int n_src, int n_dst) {
    __shared__ int chunk[256];
    int t = threadIdx.x;
    for (int i = t; i < n_src; i += 256)
        nsrc[i] = rsqrtf(fmaxf((float)deg_out[i], 1.0f));
    for (int i = t; i < n_dst; i += 256)
        ndst[i] = rsqrtf(fmaxf((float)deg_in[i], 1.0f));
    int per = (n_dst + 255) / 256;
    int lo = t * per;
    int hi = lo + per; if (hi > n_dst) hi = n_dst;
    int s = 0;
    for (int i = lo; i < hi; ++i) s += deg_in[i];
    chunk[t] = s;
    __syncthreads();
    if (t == 0) {
        int a = 0;
        for (int k = 0; k < 256; ++k) { int v = chunk[k]; chunk[k] = a; a += v; }
        row_start[n_dst] = a;
    }
    __syncthreads();
    int a = chunk[t];
    for (int i = lo; i < hi; ++i) {
        row_start[i] = a;
        cursor[i] = a;
        a += deg_in[i];
    }
}

// CSR placement: slot via int atomic (order within a row is irrelevant for +).
__global__ void v21_place(const int* __restrict__ esrc, const int* __restrict__ edst,
                          int* __restrict__ cursor, int* __restrict__ sorted_src,
                          int E, int n_src, int n_dst) {
    int i = blockIdx.x * blockDim.x + threadIdx.x;
    if (i >= E) return;
    int s = esrc[i];
    int d = edst[i];
    if ((unsigned)s >= (unsigned)n_src) return;
    if ((unsigned)d >= (unsigned)n_dst) return;
    int slot = atomicAdd(&cursor[d], 1);
    sorted_src[slot] = s;
}

// Deterministic gather: one wave per dst row, lane = feature.
// Replaces 80M fp32 atomics (351 MB HBM RMW writes) with register accum;
// writes only the 12.8 MB output. feat (25.6 MB) is L3-resident.
__global__ void v21_gather(const float* __restrict__ feat,
                           const int* __restrict__ sorted_src,
                           const int* __restrict__ row_start,
                           const float* __restrict__ nsrc,
                           const float* __restrict__ ndst,
                           float* __restrict__ out,
                           int n_src, int n_dst) {
    int gid = blockIdx.x * blockDim.x + threadIdx.x;
    int d = gid >> 6;
    int f = threadIdx.x & 63;
    if (d >= n_dst) return;
    int lo = row_start[d], hi = row_start[d + 1];
    float acc = 0.0f;
    for (int k = lo; k < hi; ++k) {
        int s = sorted_src[k];
        if ((unsigned)s >= (unsigned)n_src) continue;   // poison guard
        acc += feat[s * NFEAT + f] * nsrc[s];
    }
    out[d * NFEAT + f] = acc * ndst[d];
}

extern "C" void kernel_launch(void* const* d_in, const int* in_sizes, int n_in,
                              void* d_out, int out_size, void* d_ws, size_t ws_size,
                              hipStream_t stream) {
    const float* feat = (const float*)d_in[0];
    const int* esrc = (const int*)d_in[1];
    const int* edst = (const int*)d_in[2];
    float* out = (float*)d_out;

    const int n_src = in_sizes[0] / NFEAT;   // 100000
    const int E     = in_sizes[1];           // 1250000
    const int n_dst = out_size / NFEAT;      // 50000

    // ws: deg_out[n_src] deg_in[n_dst] nsrc[n_src] ndst[n_dst]
    //     row_start[n_dst+1] cursor[n_dst] sorted_src[E]   (~6.6 MB)
    char* ws = (char*)d_ws;
    size_t off = 0;
    int*   deg_out    = (int*)(ws + off);   off += (size_t)n_src * 4;
    int*   deg_in     = (int*)(ws + off);   off += (size_t)n_dst * 4;
    float* nsrc       = (float*)(ws + off); off += (size_t)n_src * 4;
    float* ndst       = (float*)(ws + off); off += (size_t)n_dst * 4;
    int*   row_start  = (int*)(ws + off);   off += (size_t)(n_dst + 1) * 4;
    int*   cursor     = (int*)(ws + off);   off += (size_t)n_dst * 4;
    int*   sorted_src = (int*)(ws + off);   off += (size_t)E * 4;

    const int B = 256;
    int nmax = n_src > n_dst ? n_src : n_dst;

    v21_zero<<<(nmax + B - 1) / B, B, 0, stream>>>(deg_out, deg_in, n_src, n_dst);
    v21_deg<<<(E + B - 1) / B, B, 0, stream>>>(esrc, edst, deg_out, deg_in,
                                               E, n_src, n_dst);
    v21_scan<<<1, B, 0, stream>>>(deg_out, deg_in, nsrc, ndst, row_start, cursor,
                                  n_src, n_dst);
    v21_place<<<(E + B - 1) / B, B, 0, stream>>>(esrc, edst, cursor, sorted_src,
                                                 E, n_src, n_dst);
    long long gthreads = (long long)n_dst * 64;
    v21_gather<<<(int)((gthreads + B - 1) / B), B, 0, stream>>>(feat, sorted_src,
                                                                row_start, nsrc, ndst,
                                                                out, n_src, n_dst);
}

// Round 22
// 409.118 us; speedup vs baseline: 1.5772x; 1.5772x over previous
//
#include <hip/hip_runtime.h>

#define NFEAT 64

// Environment (proven): feat=f32, indices=int32, e1=src, e2=dst, out=f32.

__global__ void v22_zero(int* __restrict__ deg_out, int* __restrict__ deg_in,
                         int n_src, int n_dst) {
    int i = blockIdx.x * blockDim.x + threadIdx.x;
    if (i < n_src) deg_out[i] = 0;
    if (i < n_dst) deg_in[i] = 0;
}

__global__ void v22_deg(const int* __restrict__ esrc, const int* __restrict__ edst,
                        int* __restrict__ deg_out, int* __restrict__ deg_in,
                        int E, int n_src, int n_dst) {
    int i = blockIdx.x * blockDim.x + threadIdx.x;
    if (i >= E) return;
    int s = esrc[i];
    int d = edst[i];
    if ((unsigned)s < (unsigned)n_src) atomicAdd(&deg_out[s], 1);
    if ((unsigned)d < (unsigned)n_dst) atomicAdd(&deg_in[d], 1);
}

// Grid-wide norms (R21's single-block version was the 271 us bottleneck).
__global__ void v22_norm(const int* __restrict__ deg_out, const int* __restrict__ deg_in,
                         float* __restrict__ nsrc, float* __restrict__ ndst,
                         int n_src, int n_dst) {
    int i = blockIdx.x * blockDim.x + threadIdx.x;
    if (i < n_src) nsrc[i] = rsqrtf(fmaxf((float)deg_out[i], 1.0f));
    if (i < n_dst) ndst[i] = rsqrtf(fmaxf((float)deg_in[i], 1.0f));
}

// ---- 3-phase parallel exclusive scan of deg_in (n_dst=50k) ----
#define SCAN_BLOCKS 128

// Phase 1: per-block partial sums.
__global__ void v22_scan1(const int* __restrict__ deg_in, int* __restrict__ bsum,
                          int n_dst, int chunk) {
    __shared__ int red[256];
    int b = blockIdx.x, t = threadIdx.x;
    int lo = b * chunk;
    int hi = lo + chunk; if (hi > n_dst) hi = n_dst;
    int s = 0;
    for (int i = lo + t; i < hi; i += 256) s += deg_in[i];
    red[t] = s;
    __syncthreads();
    for (int o = 128; o > 0; o >>= 1) {
        if (t < o) red[t] += red[t + o];
        __syncthreads();
    }
    if (t == 0) bsum[b] = red[0];
}

// Phase 2: exclusive scan of the 128 block sums; total -> row_start[n_dst].
__global__ void v22_scan2(int* __restrict__ bsum, int* __restrict__ boff,
                          int* __restrict__ row_start, int n_dst) {
    if (threadIdx.x == 0) {
        int a = 0;
        for (int k = 0; k < SCAN_BLOCKS; ++k) { boff[k] = a; a += bsum[k]; }
        row_start[n_dst] = a;
    }
}

// Phase 3: per-block fill of row_start/cursor with LDS thread-prefix.
__global__ void v22_scan3(const int* __restrict__ deg_in, const int* __restrict__ boff,
                          int* __restrict__ row_start, int* __restrict__ cursor,
                          int n_dst, int chunk) {
    __shared__ int tsum[256];
    int b = blockIdx.x, t = threadIdx.x;
    int lo = b * chunk;
    int hi = lo + chunk; if (hi > n_dst) hi = n_dst;
    int per = (chunk + 255) / 256;
    int mylo = lo + t * per;
    int myhi = mylo + per; if (myhi > hi) myhi = hi;
    int s = 0;
    for (int i = mylo; i < myhi; ++i) s += deg_in[i];
    tsum[t] = s;
    __syncthreads();
    if (t == 0) {
        int a = 0;
        for (int k = 0; k < 256; ++k) { int v = tsum[k]; tsum[k] = a; a += v; }
    }
    __syncthreads();
    int a = boff[b] + tsum[t];
    for (int i = mylo; i < myhi; ++i) {
        row_start[i] = a;
        cursor[i] = a;
        a += deg_in[i];
    }
}

// CSR placement via int atomics on cursors.
__global__ void v22_place(const int* __restrict__ esrc, const int* __restrict__ edst,
                          int* __restrict__ cursor, int* __restrict__ sorted_src,
                          int E, int n_src, int n_dst) {
    int i = blockIdx.x * blockDim.x + threadIdx.x;
    if (i >= E) return;
    int s = esrc[i];
    int d = edst[i];
    if ((unsigned)s >= (unsigned)n_src) return;
    if ((unsigned)d >= (unsigned)n_dst) return;
    int slot = atomicAdd(&cursor[d], 1);
    sorted_src[slot] = s;
}

// Deterministic gather: one wave per dst row, lane = feature.
__global__ void v22_gather(const float* __restrict__ feat,
                           const int* __restrict__ sorted_src,
                           const int* __restrict__ row_start,
                           const float* __restrict__ nsrc,
                           const float* __restrict__ ndst,
                           float* __restrict__ out,
                           int n_src, int n_dst) {
    int gid = blockIdx.x * blockDim.x + threadIdx.x;
    int d = gid >> 6;
    int f = threadIdx.x & 63;
    if (d >= n_dst) return;
    int lo = row_start[d], hi = row_start[d + 1];
    float acc = 0.0f;
    for (int k = lo; k < hi; ++k) {
        int s = sorted_src[k];
        if ((unsigned)s >= (unsigned)n_src) continue;   // poison guard
        acc += feat[s * NFEAT + f] * nsrc[s];
    }
    out[d * NFEAT + f] = acc * ndst[d];
}

extern "C" void kernel_launch(void* const* d_in, const int* in_sizes, int n_in,
                              void* d_out, int out_size, void* d_ws, size_t ws_size,
                              hipStream_t stream) {
    const float* feat = (const float*)d_in[0];
    const int* esrc = (const int*)d_in[1];
    const int* edst = (const int*)d_in[2];
    float* out = (float*)d_out;

    const int n_src = in_sizes[0] / NFEAT;   // 100000
    const int E     = in_sizes[1];           // 1250000
    const int n_dst = out_size / NFEAT;      // 50000

    // ws: deg_out[n_src] deg_in[n_dst] nsrc[n_src] ndst[n_dst]
    //     row_start[n_dst+1] cursor[n_dst] bsum[128] boff[128] sorted_src[E]
    char* ws = (char*)d_ws;
    size_t off = 0;
    int*   deg_out    = (int*)(ws + off);   off += (size_t)n_src * 4;
    int*   deg_in     = (int*)(ws + off);   off += (size_t)n_dst * 4;
    float* nsrc       = (float*)(ws + off); off += (size_t)n_src * 4;
    float* ndst       = (float*)(ws + off); off += (size_t)n_dst * 4;
    int*   row_start  = (int*)(ws + off);   off += (size_t)(n_dst + 1) * 4;
    int*   cursor     = (int*)(ws + off);   off += (size_t)n_dst * 4;
    int*   bsum       = (int*)(ws + off);   off += SCAN_BLOCKS * 4;
    int*   boff       = (int*)(ws + off);   off += SCAN_BLOCKS * 4;
    int*   sorted_src = (int*)(ws + off);   off += (size_t)E * 4;

    const int B = 256;
    int nmax = n_src > n_dst ? n_src : n_dst;
    int chunk = (n_dst + SCAN_BLOCKS - 1) / SCAN_BLOCKS;

    v22_zero<<<(nmax + B - 1) / B, B, 0, stream>>>(deg_out, deg_in, n_src, n_dst);
    v22_deg<<<(E + B - 1) / B, B, 0, stream>>>(esrc, edst, deg_out, deg_in,
                                               E, n_src, n_dst);
    v22_norm<<<(nmax + B - 1) / B, B, 0, stream>>>(deg_out, deg_in, nsrc, ndst,
                                                   n_src, n_dst);
    v22_scan1<<<SCAN_BLOCKS, B, 0, stream>>>(deg_in, bsum, n_dst, chunk);
    v22_scan2<<<1, 64, 0, stream>>>(bsum, boff, row_start, n_dst);
    v22_scan3<<<SCAN_BLOCKS, B, 0, stream>>>(deg_in, boff, row_start, cursor,
                                             n_dst, chunk);
    v22_place<<<(E + B - 1) / B, B, 0, stream>>>(esrc, edst, cursor, sorted_src,
                                                 E, n_src, n_dst);
    long long gthreads = (long long)n_dst * 64;
    v22_gather<<<(int)((gthreads + B - 1) / B), B, 0, stream>>>(feat, sorted_src,
                                                                row_start, nsrc, ndst,
                                                                out, n_src, n_dst);
}

// Round 23
// 339.090 us; speedup vs baseline: 1.9029x; 1.2065x over previous
//
#include <hip/hip_runtime.h>

#define NFEAT 64

// Environment (proven): feat=f32, indices=int32, e1=src, e2=dst, out=f32.

__global__ void v23_zero(int* __restrict__ deg_out, int* __restrict__ deg_in,
                         int n_src, int n_dst) {
    int i = blockIdx.x * blockDim.x + threadIdx.x;
    if (i < n_src) deg_out[i] = 0;
    if (i < n_dst) deg_in[i] = 0;
}

__global__ void v23_deg(const int* __restrict__ esrc, const int* __restrict__ edst,
                        int* __restrict__ deg_out, int* __restrict__ deg_in,
                        int E, int n_src, int n_dst) {
    int i = blockIdx.x * blockDim.x + threadIdx.x;
    if (i >= E) return;
    int s = esrc[i];
    int d = edst[i];
    if ((unsigned)s < (unsigned)n_src) atomicAdd(&deg_out[s], 1);
    if ((unsigned)d < (unsigned)n_dst) atomicAdd(&deg_in[d], 1);
}

__global__ void v23_norm(const int* __restrict__ deg_out, const int* __restrict__ deg_in,
                         float* __restrict__ nsrc, float* __restrict__ ndst,
                         int n_src, int n_dst) {
    int i = blockIdx.x * blockDim.x + threadIdx.x;
    if (i < n_src) nsrc[i] = rsqrtf(fmaxf((float)deg_out[i], 1.0f));
    if (i < n_dst) ndst[i] = rsqrtf(fmaxf((float)deg_in[i], 1.0f));
}

#define SCAN_BLOCKS 128

__global__ void v23_scan1(const int* __restrict__ deg_in, int* __restrict__ bsum,
                          int n_dst, int chunk) {
    __shared__ int red[256];
    int b = blockIdx.x, t = threadIdx.x;
    int lo = b * chunk;
    int hi = lo + chunk; if (hi > n_dst) hi = n_dst;
    int s = 0;
    for (int i = lo + t; i < hi; i += 256) s += deg_in[i];
    red[t] = s;
    __syncthreads();
    for (int o = 128; o > 0; o >>= 1) {
        if (t < o) red[t] += red[t + o];
        __syncthreads();
    }
    if (t == 0) bsum[b] = red[0];
}

__global__ void v23_scan2(int* __restrict__ bsum, int* __restrict__ boff,
                          int* __restrict__ row_start, int n_dst) {
    if (threadIdx.x == 0) {
        int a = 0;
        for (int k = 0; k < SCAN_BLOCKS; ++k) { boff[k] = a; a += bsum[k]; }
        row_start[n_dst] = a;
    }
}

__global__ void v23_scan3(const int* __restrict__ deg_in, const int* __restrict__ boff,
                          int* __restrict__ row_start, int* __restrict__ cursor,
                          int n_dst, int chunk) {
    __shared__ int tsum[256];
    int b = blockIdx.x, t = threadIdx.x;
    int lo = b * chunk;
    int hi = lo + chunk; if (hi > n_dst) hi = n_dst;
    int per = (chunk + 255) / 256;
    int mylo = lo + t * per;
    int myhi = mylo + per; if (myhi > hi) myhi = hi;
    int s = 0;
    for (int i = mylo; i < myhi; ++i) s += deg_in[i];
    tsum[t] = s;
    __syncthreads();
    if (t == 0) {
        int a = 0;
        for (int k = 0; k < 256; ++k) { int v = tsum[k]; tsum[k] = a; a += v; }
    }
    __syncthreads();
    int a = boff[b] + tsum[t];
    for (int i = mylo; i < myhi; ++i) {
        row_start[i] = a;
        cursor[i] = a;
        a += deg_in[i];
    }
}

__global__ void v23_place(const int* __restrict__ esrc, const int* __restrict__ edst,
                          int* __restrict__ cursor, int* __restrict__ sorted_src,
                          int E, int n_src, int n_dst) {
    int i = blockIdx.x * blockDim.x + threadIdx.x;
    if (i >= E) return;
    int s = esrc[i];
    int d = edst[i];
    if ((unsigned)s >= (unsigned)n_src) return;
    if ((unsigned)d >= (unsigned)n_dst) return;
    int slot = atomicAdd(&cursor[d], 1);
    sorted_src[slot] = s;
}

// Gather, 4x unrolled: 4 independent feat-row loads in flight per wave
// (R22 was MLP-bound: 1 outstanding row/wave -> 1.2 TB/s of ~2.5 TB/s
// latency-capacity). Indices clamped branchlessly (ranges proven; clamp
// only defends against unwritten-slot poison).
__global__ void v23_gather(const float* __restrict__ feat,
                           const int* __restrict__ sorted_src,
                           const int* __restrict__ row_start,
                           const float* __restrict__ nsrc,
                           const float* __restrict__ ndst,
                           float* __restrict__ out,
                           int n_src, int n_dst) {
    int gid = blockIdx.x * blockDim.x + threadIdx.x;
    int d = gid >> 6;
    int f = threadIdx.x & 63;
    if (d >= n_dst) return;
    int lo = row_start[d], hi = row_start[d + 1];
    int nmax = n_src - 1;
    float a0 = 0.0f, a1 = 0.0f, a2 = 0.0f, a3 = 0.0f;
    int k = lo;
    for (; k + 3 < hi; k += 4) {
        int s0 = sorted_src[k];
        int s1 = sorted_src[k + 1];
        int s2 = sorted_src[k + 2];
        int s3 = sorted_src[k + 3];
        s0 = min(max(s0, 0), nmax);
        s1 = min(max(s1, 0), nmax);
        s2 = min(max(s2, 0), nmax);
        s3 = min(max(s3, 0), nmax);
        float v0 = feat[(size_t)s0 * NFEAT + f];
        float v1 = feat[(size_t)s1 * NFEAT + f];
        float v2 = feat[(size_t)s2 * NFEAT + f];
        float v3 = feat[(size_t)s3 * NFEAT + f];
        a0 += v0 * nsrc[s0];
        a1 += v1 * nsrc[s1];
        a2 += v2 * nsrc[s2];
        a3 += v3 * nsrc[s3];
    }
    for (; k < hi; ++k) {
        int s = sorted_src[k];
        s = min(max(s, 0), nmax);
        a0 += feat[(size_t)s * NFEAT + f] * nsrc[s];
    }
    out[d * NFEAT + f] = ((a0 + a1) + (a2 + a3)) * ndst[d];
}

extern "C" void kernel_launch(void* const* d_in, const int* in_sizes, int n_in,
                              void* d_out, int out_size, void* d_ws, size_t ws_size,
                              hipStream_t stream) {
    const float* feat = (const float*)d_in[0];
    const int* esrc = (const int*)d_in[1];
    const int* edst = (const int*)d_in[2];
    float* out = (float*)d_out;

    const int n_src = in_sizes[0] / NFEAT;   // 100000
    const int E     = in_sizes[1];           // 1250000
    const int n_dst = out_size / NFEAT;      // 50000

    // ws: deg_out[n_src] deg_in[n_dst] nsrc[n_src] ndst[n_dst]
    //     row_start[n_dst+1] cursor[n_dst] bsum[128] boff[128] sorted_src[E]
    char* ws = (char*)d_ws;
    size_t off = 0;
    int*   deg_out    = (int*)(ws + off);   off += (size_t)n_src * 4;
    int*   deg_in     = (int*)(ws + off);   off += (size_t)n_dst * 4;
    float* nsrc       = (float*)(ws + off); off += (size_t)n_src * 4;
    float* ndst       = (float*)(ws + off); off += (size_t)n_dst * 4;
    int*   row_start  = (int*)(ws + off);   off += (size_t)(n_dst + 1) * 4;
    int*   cursor     = (int*)(ws + off);   off += (size_t)n_dst * 4;
    int*   bsum       = (int*)(ws + off);   off += SCAN_BLOCKS * 4;
    int*   boff       = (int*)(ws + off);   off += SCAN_BLOCKS * 4;
    int*   sorted_src = (int*)(ws + off);   off += (size_t)E * 4;

    const int B = 256;
    int nmax = n_src > n_dst ? n_src : n_dst;
    int chunk = (n_dst + SCAN_BLOCKS - 1) / SCAN_BLOCKS;

    v23_zero<<<(nmax + B - 1) / B, B, 0, stream>>>(deg_out, deg_in, n_src, n_dst);
    v23_deg<<<(E + B - 1) / B, B, 0, stream>>>(esrc, edst, deg_out, deg_in,
                                               E, n_src, n_dst);
    v23_norm<<<(nmax + B - 1) / B, B, 0, stream>>>(deg_out, deg_in, nsrc, ndst,
                                                   n_src, n_dst);
    v23_scan1<<<SCAN_BLOCKS, B, 0, stream>>>(deg_in, bsum, n_dst, chunk);
    v23_scan2<<<1, 64, 0, stream>>>(bsum, boff, row_start, n_dst);
    v23_scan3<<<SCAN_BLOCKS, B, 0, stream>>>(deg_in, boff, row_start, cursor,
                                             n_dst, chunk);
    v23_place<<<(E + B - 1) / B, B, 0, stream>>>(esrc, edst, cursor, sorted_src,
                                                 E, n_src, n_dst);
    long long gthreads = (long long)n_dst * 64;
    v23_gather<<<(int)((gthreads + B - 1) / B), B, 0, stream>>>(feat, sorted_src,
                                                                row_start, nsrc, ndst,
                                                                out, n_src, n_dst);
}